// Round 2
// baseline (1090.163 us; speedup 1.0000x reference)
//
#include <hip/hip_runtime.h>
#include <hip/hip_bf16.h>

// ---------------------------------------------------------------------------
// GCN: 3x (GEMM -> sym-normalized aggregation(+self-loop) -> +bias -> ReLU)
//      -> global max pool per graph -> MLP head.
// All fp32 (accuracy threshold forbids bf16 on the node GEMMs).
// Aggregation via CSR (built per call) gather: deterministic work, no float
// atomics on the 51MB feature buffers.
// ---------------------------------------------------------------------------

__global__ void deg_count_kernel(const int* __restrict__ ei, int* __restrict__ cnt, int E) {
    int e = blockIdx.x * 256 + threadIdx.x;
    if (e < E) atomicAdd(&cnt[ei[E + e]], 1);
}

__global__ void deg_fin_kernel(const int* __restrict__ cnt, float* __restrict__ disq, int N) {
    int i = blockIdx.x * 256 + threadIdx.x;
    if (i < N) disq[i] = rsqrtf((float)cnt[i] + 1.0f);
}

// ---- 2-level exclusive scan of cnt[N] -> rp[N] (chunk = 1024 = 256 thr x 4)
__global__ void scan_pass1(const int* __restrict__ cnt, int* __restrict__ bsum, int N) {
    __shared__ int s[256];
    int t = threadIdx.x;
    int base = blockIdx.x * 1024 + t * 4;
    int sum = 0;
    #pragma unroll
    for (int j = 0; j < 4; ++j) { int idx = base + j; if (idx < N) sum += cnt[idx]; }
    s[t] = sum; __syncthreads();
    for (int off = 128; off; off >>= 1) {
        if (t < off) s[t] += s[t + off];
        __syncthreads();
    }
    if (t == 0) bsum[blockIdx.x] = s[0];
}

__global__ void scan_pass2(const int* __restrict__ bsum, int* __restrict__ boff,
                           int nchunks, int* __restrict__ rp, int N, int E) {
    __shared__ int s[256];
    int t = threadIdx.x;
    int v = (t < nchunks) ? bsum[t] : 0;
    s[t] = v; __syncthreads();
    for (int off = 1; off < 256; off <<= 1) {
        int x = (t >= off) ? s[t - off] : 0;
        __syncthreads();
        s[t] += x;
        __syncthreads();
    }
    boff[t] = s[t] - v;           // exclusive
    if (t == 0) rp[N] = E;
}

__global__ void scan_pass3(const int* __restrict__ cnt, const int* __restrict__ boff,
                           int* __restrict__ rp, int N) {
    __shared__ int s[256];
    int t = threadIdx.x;
    int base = blockIdx.x * 1024 + t * 4;
    int v[4]; int sum = 0;
    #pragma unroll
    for (int j = 0; j < 4; ++j) { int idx = base + j; v[j] = (idx < N) ? cnt[idx] : 0; sum += v[j]; }
    s[t] = sum; __syncthreads();
    for (int off = 1; off < 256; off <<= 1) {
        int x = (t >= off) ? s[t - off] : 0;
        __syncthreads();
        s[t] += x;
        __syncthreads();
    }
    int ex = s[t] - sum + boff[blockIdx.x];
    #pragma unroll
    for (int j = 0; j < 4; ++j) { int idx = base + j; if (idx < N) { rp[idx] = ex; ex += v[j]; } }
}

__global__ void scatter_kernel(const int* __restrict__ ei, const float* __restrict__ disq,
                               const int* __restrict__ rp, int* __restrict__ fill,
                               int* __restrict__ srcs, float* __restrict__ nv, int E) {
    int e = blockIdx.x * 256 + threadIdx.x;
    if (e >= E) return;
    int s = ei[e];
    int d = ei[E + e];
    int pos = rp[d] + atomicAdd(&fill[d], 1);
    srcs[pos] = s;
    nv[pos] = disq[s] * disq[d];
}

// ---- fp32 GEMM: C[N,NOUT] = A[N,K] @ W[K,NOUT]   (no bias; bias fused in agg)
// 64-row tile, BK=32, 256 threads, each thread 4 rows x (NOUT/16) cols.
template <int NOUT>
__global__ __launch_bounds__(256) void gemm_kernel(
    const float* __restrict__ A, const float* __restrict__ W,
    float* __restrict__ C, int N, int K)
{
    constexpr int BM = 64, BK = 32;
    constexpr int CPT = NOUT / 16;
    __shared__ float As[BM][BK + 1];
    __shared__ float Ws[BK][NOUT + 4];
    int tid = threadIdx.x;
    int tr = tid >> 4;   // 0..15 -> 4 rows each
    int tc = tid & 15;   // 0..15 -> cols tc+16*j
    long base = (long)blockIdx.x * BM;

    float acc[4][CPT];
    #pragma unroll
    for (int i = 0; i < 4; ++i)
        #pragma unroll
        for (int j = 0; j < CPT; ++j) acc[i][j] = 0.f;

    for (int k0 = 0; k0 < K; k0 += BK) {
        for (int idx = tid; idx < BM * BK; idx += 256) {
            int r = idx >> 5, k = idx & 31;
            long row = base + r;
            As[r][k] = (row < N && (k0 + k) < K) ? A[row * K + k0 + k] : 0.f;
        }
        for (int idx = tid; idx < BK * NOUT; idx += 256) {
            int k = idx / NOUT, c = idx % NOUT;
            Ws[k][c] = ((k0 + k) < K) ? W[(long)(k0 + k) * NOUT + c] : 0.f;
        }
        __syncthreads();
        #pragma unroll
        for (int k = 0; k < BK; ++k) {
            float a0 = As[tr * 4 + 0][k];
            float a1 = As[tr * 4 + 1][k];
            float a2 = As[tr * 4 + 2][k];
            float a3 = As[tr * 4 + 3][k];
            #pragma unroll
            for (int j = 0; j < CPT; ++j) {
                float w = Ws[k][tc + 16 * j];
                acc[0][j] += a0 * w;
                acc[1][j] += a1 * w;
                acc[2][j] += a2 * w;
                acc[3][j] += a3 * w;
            }
        }
        __syncthreads();
    }
    #pragma unroll
    for (int i = 0; i < 4; ++i) {
        long row = base + tr * 4 + i;
        if (row < N) {
            #pragma unroll
            for (int j = 0; j < CPT; ++j)
                C[row * NOUT + tc + 16 * j] = acc[i][j];
        }
    }
}

// ---- aggregation: h[i] = relu( sum_{e in CSR(i)} xw[src_e]*nv_e + xw[i]*disq[i]^2 + bias )
// one wave (64 threads) per node
template <int C>
__global__ void agg_kernel(const float* __restrict__ xw, const float* __restrict__ disq,
                           const int* __restrict__ rp, const int* __restrict__ srcs,
                           const float* __restrict__ nv, const float* __restrict__ bias,
                           float* __restrict__ h, int N)
{
    int i = blockIdx.x;
    if (i >= N) return;
    int lane = threadIdx.x;   // 0..63
    int e0 = rp[i], e1 = rp[i + 1];
    if constexpr (C == 128) {
        const float2* xw2 = (const float2*)xw;
        float2 acc; acc.x = 0.f; acc.y = 0.f;
        for (int e = e0; e < e1; ++e) {
            int s = srcs[e];
            float w = nv[e];
            float2 v = xw2[(long)s * 64 + lane];
            acc.x += v.x * w;
            acc.y += v.y * w;
        }
        float ds = disq[i];
        float wself = ds * ds;
        float2 v = xw2[(long)i * 64 + lane];
        acc.x += v.x * wself;
        acc.y += v.y * wself;
        float2 b = ((const float2*)bias)[lane];
        acc.x = fmaxf(acc.x + b.x, 0.f);
        acc.y = fmaxf(acc.y + b.y, 0.f);
        ((float2*)h)[(long)i * 64 + lane] = acc;
    } else {   // C == 64
        float acc = 0.f;
        for (int e = e0; e < e1; ++e) {
            int s = srcs[e];
            float w = nv[e];
            acc += xw[(long)s * 64 + lane] * w;
        }
        float ds = disq[i];
        acc += xw[(long)i * 64 + lane] * ds * ds;
        acc = fmaxf(acc + bias[lane], 0.f);
        h[(long)i * 64 + lane] = acc;
    }
}

// ---- global max pool: g[batch[n]][c] = max over nodes (values >= 0 post-ReLU)
__global__ void pool_kernel(const float* __restrict__ h, const int* __restrict__ batch,
                            float* __restrict__ g, int N) {
    int total = N * 64;
    for (int idx = blockIdx.x * blockDim.x + threadIdx.x; idx < total;
         idx += gridDim.x * blockDim.x) {
        int node = idx >> 6;
        int c = idx & 63;
        float v = h[idx];
        int b = batch[node];
        atomicMax((int*)&g[b * 64 + c], __float_as_int(v));
    }
}

// ---- head: out[r] = relu(g[r]@Wh1+bh1) @ Wh2 + bh2
__global__ void head_kernel(const float* __restrict__ g, const float* __restrict__ Wh1,
                            const float* __restrict__ bh1, const float* __restrict__ Wh2,
                            const float* __restrict__ bh2, float* __restrict__ out, int G) {
    int r = threadIdx.x;
    if (r >= G) return;
    float hid[32];
    #pragma unroll
    for (int j = 0; j < 32; ++j) {
        float s = bh1[j];
        for (int k = 0; k < 64; ++k) s += g[r * 64 + k] * Wh1[k * 32 + j];
        hid[j] = fmaxf(s, 0.f);
    }
    float o = bh2[0];
    #pragma unroll
    for (int j = 0; j < 32; ++j) o += hid[j] * Wh2[j];
    out[r] = o;
}

extern "C" void kernel_launch(void* const* d_in, const int* in_sizes, int n_in,
                              void* d_out, int out_size, void* d_ws, size_t ws_size,
                              hipStream_t stream) {
    const float* x   = (const float*)d_in[0];
    const int*   ei  = (const int*)d_in[1];
    const int*   bat = (const int*)d_in[2];
    const float* W1  = (const float*)d_in[3];
    const float* b1  = (const float*)d_in[4];
    const float* W2  = (const float*)d_in[5];
    const float* b2  = (const float*)d_in[6];
    const float* W3  = (const float*)d_in[7];
    const float* b3  = (const float*)d_in[8];
    const float* Wh1 = (const float*)d_in[9];
    const float* bh1 = (const float*)d_in[10];
    const float* Wh2 = (const float*)d_in[11];
    const float* bh2 = (const float*)d_in[12];
    float* out = (float*)d_out;

    const int N = in_sizes[2];
    const int E = in_sizes[1] / 2;
    const int K1 = in_sizes[0] / N;   // 397
    const int G = out_size;           // 64

    // bump allocator on workspace
    char* wsp = (char*)d_ws;
    size_t off = 0;
    auto alloc = [&](size_t bytes) -> void* {
        void* p = wsp + off;
        off = (off + bytes + 255) & ~(size_t)255;
        return p;
    };
    int*   cnt  = (int*)alloc((size_t)N * 4);          // also reused as fill
    float* disq = (float*)alloc((size_t)N * 4);
    int*   rp   = (int*)alloc((size_t)(N + 1) * 4);
    int*   bsum = (int*)alloc(256 * 4);
    int*   boff = (int*)alloc(256 * 4);
    int*   srcs = (int*)alloc((size_t)E * 4);
    float* nv   = (float*)alloc((size_t)E * 4);
    float* B0   = (float*)alloc((size_t)N * 128 * 4);
    float* B1   = (float*)alloc((size_t)N * 128 * 4);
    float* g    = (float*)alloc((size_t)G * 64 * 4);

    const int nchunks = (N + 1023) / 1024;   // <= 256 assumed (98 here)

    (void)hipMemsetAsync(cnt, 0, (size_t)N * 4, stream);
    deg_count_kernel<<<(E + 255) / 256, 256, 0, stream>>>(ei, cnt, E);
    deg_fin_kernel<<<(N + 255) / 256, 256, 0, stream>>>(cnt, disq, N);
    scan_pass1<<<nchunks, 256, 0, stream>>>(cnt, bsum, N);
    scan_pass2<<<1, 256, 0, stream>>>(bsum, boff, nchunks, rp, N, E);
    scan_pass3<<<nchunks, 256, 0, stream>>>(cnt, boff, rp, N);
    (void)hipMemsetAsync(cnt, 0, (size_t)N * 4, stream);
    scatter_kernel<<<(E + 255) / 256, 256, 0, stream>>>(ei, disq, rp, cnt, srcs, nv, E);

    int gblocks = (N + 63) / 64;
    // layer 1
    gemm_kernel<128><<<gblocks, 256, 0, stream>>>(x, W1, B0, N, K1);
    agg_kernel<128><<<N, 64, 0, stream>>>(B0, disq, rp, srcs, nv, b1, B1, N);
    // layer 2
    gemm_kernel<128><<<gblocks, 256, 0, stream>>>(B1, W2, B0, N, 128);
    agg_kernel<128><<<N, 64, 0, stream>>>(B0, disq, rp, srcs, nv, b2, B1, N);
    // layer 3
    gemm_kernel<64><<<gblocks, 256, 0, stream>>>(B1, W3, B0, N, 128);
    agg_kernel<64><<<N, 64, 0, stream>>>(B0, disq, rp, srcs, nv, b3, B1, N);
    // pool + head
    (void)hipMemsetAsync(g, 0, (size_t)G * 64 * 4, stream);
    pool_kernel<<<1024, 256, 0, stream>>>(B1, bat, g, N);
    head_kernel<<<1, 64, 0, stream>>>(g, Wh1, bh1, Wh2, bh2, out, G);
}